// Round 18
// baseline (214.190 us; speedup 1.0000x reference)
//
#include <hip/hip_runtime.h>
#include <math.h>

#define BDIM 256

typedef float v2f __attribute__((ext_vector_type(2)));
typedef float v4f __attribute__((ext_vector_type(4)));

__device__ __forceinline__ v2f pkfma(v2f a, v2f b, v2f c) {
#if __has_builtin(__builtin_elementwise_fma)
  return __builtin_elementwise_fma(a, b, c);
#else
  v2f d;
  d.x = fmaf(a.x, b.x, c.x);
  d.y = fmaf(a.y, b.y, c.y);
  return d;
#endif
}

__device__ __forceinline__ v4f pkfma4(v4f a, v4f b, v4f c) {
#if __has_builtin(__builtin_elementwise_fma)
  return __builtin_elementwise_fma(a, b, c);
#else
  v4f d;
  d.x = fmaf(a.x, b.x, c.x);
  d.y = fmaf(a.y, b.y, c.y);
  d.z = fmaf(a.z, b.z, c.z);
  d.w = fmaf(a.w, b.w, c.w);
  return d;
#endif
}

// ---------------------------------------------------------------------------
// jax.image.resize (bilinear/triangle, antialias=True) tap weights.
// ---------------------------------------------------------------------------
__device__ __forceinline__ int resize_taps(int out_n, int o, int in_n,
                                           float* w, int* i0) {
  float inv_scale = (float)in_n / (float)out_n;
  float ks = inv_scale > 1.f ? inv_scale : 1.f;
  float sf = ((float)o + 0.5f) * inv_scale - 0.5f;
  int lo = (int)ceilf(sf - ks);
  int hi = (int)floorf(sf + ks);
  if (lo < 0) lo = 0;
  if (hi > in_n - 1) hi = in_n - 1;
  int n = hi - lo + 1;
  float sum = 0.f;
  for (int k = 0; k < n; ++k) {
    float t = 1.f - fabsf((float)(lo + k) - sf) / ks;
    t = t > 0.f ? t : 0.f;
    w[k] = t;
    sum += t;
  }
  float inv = 1.f / sum;
  for (int k = 0; k < n; ++k) w[k] *= inv;
  *i0 = lo;
  return n;
}

__device__ __forceinline__ float resize_one(const float* __restrict__ plane,
                                            int Hi, int Wi, int oy, int ox,
                                            int Ho, int Wo) {
  float wy[8], wx[8];
  int y0, x0;
  int ny = resize_taps(Ho, oy, Hi, wy, &y0);
  int nx = resize_taps(Wo, ox, Wi, wx, &x0);
  float acc = 0.f;
  for (int a = 0; a < ny; ++a) {
    const float* row = plane + (y0 + a) * Wi + x0;
    float r = 0.f;
    for (int b = 0; b < nx; ++b) r += wx[b] * row[b];
    acc += wy[a] * r;
  }
  return acc;
}

// Hardcoded jax 2x bilinear upsample taps (scale>1 => no antialias change).
__device__ __forceinline__ void up2(int o, int n, int* t, float* w) {
  int m = o >> 1;
  if (o == 0) { t[0] = 0; w[0] = 1.f; t[1] = 0; w[1] = 0.f; }
  else if (o == 2 * n - 1) { t[0] = n - 1; w[0] = 1.f; t[1] = n - 1; w[1] = 0.f; }
  else if (o & 1) { t[0] = m; w[0] = 0.75f; t[1] = m + 1; w[1] = 0.25f; }
  else { t[0] = m - 1; w[0] = 0.25f; t[1] = m; w[1] = 0.75f; }
}

// quad-layout store: channel c, pixel pix, plane size HW (floats)
__device__ __forceinline__ void pstore4(float* __restrict__ dst, int c, int pix,
                                        int HW, float v) {
  dst[((size_t)(c >> 2) * HW + pix) * 4 + (c & 3)] = v;
}

// ---------------------------------------------------------------------------
// FRONT: builds QUAD-CHANNEL [c/4][HW][4] copies of all conv inputs:
//   x1q, x2q (hardcoded 2x up taps), x3q (composed 2x·2x), xq, + wT transpose.
// ---------------------------------------------------------------------------
__global__ void k_front(const float* __restrict__ x, float* __restrict__ x1q,
                        float* __restrict__ x2q, float* __restrict__ x3q,
                        float* __restrict__ xq,
                        const float* __restrict__ d0, const float* __restrict__ d1,
                        const float* __restrict__ d2, const float* __restrict__ d3,
                        const float* __restrict__ c0, const float* __restrict__ c1,
                        const float* __restrict__ c2, const float* __restrict__ c3,
                        float* __restrict__ wT) {
  int idx = blockIdx.x * BDIM + threadIdx.x;
  if (idx < 65536) {
    int ox = idx & 31, oy = (idx >> 5) & 31, c = idx >> 10;
    pstore4(x1q, c, oy * 32 + ox, 1024,
            resize_one(x + c * 4096, 64, 64, oy, ox, 32, 32));
  } else if (idx < 1114112) {
    int j = idx - 65536;
    int ox = j & 127, oy = (j >> 7) & 127, c = j >> 14;
    int ty[2], tx[2];
    float twy[2], twx[2];
    up2(oy, 64, ty, twy);
    up2(ox, 64, tx, twx);
    const float* xc = x + c * 4096;
    float acc = 0.f;
#pragma unroll
    for (int a = 0; a < 2; ++a) {
      const float* row = xc + ty[a] * 64;
      acc += twy[a] * (twx[0] * row[tx[0]] + twx[1] * row[tx[1]]);
    }
    pstore4(x2q, c, oy * 128 + ox, 16384, acc);
  } else if (idx < 5308416) {
    int j = idx - 1114112;
    int ox = j & 255, oy = (j >> 8) & 255, c = j >> 16;
    int ty[2], tx[2];
    float twy[2], twx[2];
    up2(oy, 128, ty, twy);
    up2(ox, 128, tx, twx);
    int ry[4], rx[4];
    float rwy[4], rwx[4];
#pragma unroll
    for (int a = 0; a < 2; ++a) {
      int t2[2];
      float w2[2];
      up2(ty[a], 64, t2, w2);
      ry[2 * a] = t2[0]; rwy[2 * a] = twy[a] * w2[0];
      ry[2 * a + 1] = t2[1]; rwy[2 * a + 1] = twy[a] * w2[1];
      up2(tx[a], 64, t2, w2);
      rx[2 * a] = t2[0]; rwx[2 * a] = twx[a] * w2[0];
      rx[2 * a + 1] = t2[1]; rwx[2 * a + 1] = twx[a] * w2[1];
    }
    const float* xc = x + c * 4096;
    float acc = 0.f;
#pragma unroll
    for (int a = 0; a < 4; ++a) {
      const float* row = xc + ry[a] * 64;
      float r = 0.f;
#pragma unroll
      for (int b = 0; b < 4; ++b) r += rwx[b] * row[rx[b]];
      acc += rwy[a] * r;
    }
    pstore4(x3q, c, oy * 256 + ox, 65536, acc);
  } else if (idx < 5386752) {
    int w = idx - 5308416;
    if (w < 36864) {
      int i = w / 9216, r = w % 9216;
      int o = r % 16, t = r / 16, c = t % 64, k = t / 64;
      const float* s = i == 0 ? d0 : i == 1 ? d1 : i == 2 ? d2 : d3;
      wT[w] = s[(o * 64 + c) * 9 + k];
    } else {
      int j = w - 36864;
      int i = j / 10368, r = j % 10368;
      int o = r % 18, t = r / 18, c = t % 64, k = t / 64;
      const float* s = i == 0 ? c0 : i == 1 ? c1 : i == 2 ? c2 : c3;
      wT[w] = s[(o * 64 + c) * 9 + k];
    }
  } else if (idx < 5648896) {
    int j = idx - 5386752;        // copy x -> quad xq
    int c = j >> 12, pix = j & 4095;
    pstore4(xq, c, pix, 4096, x[j]);
  }
}

// ---------------------------------------------------------------------------
// FUSED offset-conv + deformable conv + leaky, all 4 scales in one grid.
// QUAD-CHANNEL inputs. Segments big->small; bijective per-segment XCD swizzle.
// Block = 512 thr = 8 waves; wave g owns channels 8g..8g+7 (quads 2g,2g+1).
// PHASE-B WEIGHTS STAGED IN LDS (reusing `red`, free during phase B): kills
// the serial s_load->wait->FMA chain (128 weight floats/tap > free SGPRs, so
// the compiler could never prefetch a tap ahead -- the R17 stall diagnosis).
// launch_bounds(512,4); VGPR sweet spot <=64.
// ---------------------------------------------------------------------------
struct FArgs {
  const float* in[4];   // quad-channel images
  const float* wc[4];   // conv weights [k][c][o18]
  const float* bc[4];   // conv bias
  const float* wd[4];   // deform weights [k][c][o16] (crossed)
  const float* bd[4];   // deform bias (crossed)
  float* out[4];        // a1, a0, a2, a3 (scalar CHW)
};

__global__ __launch_bounds__(512, 4) void k_fused(FArgs A) {
  __shared__ float red[8 * 64 * 18];   // 36.9 KB; phase-A reduce, then
                                       // phase-B weight cache, then final reduce
  int b = blockIdx.x;
  int s, b0, nseg;
  if (b < 1024)      { s = 3; b0 = 0;    nseg = 1024; }
  else if (b < 1280) { s = 2; b0 = 1024; nseg = 256; }
  else if (b < 1344) { s = 1; b0 = 1280; nseg = 64; }
  else               { s = 0; b0 = 1344; nseg = 16; }
  int bl = b - b0;
  int swz = (bl & 7) * (nseg >> 3) + (bl >> 3);
  int H = 32 << s, W = H, lw = 5 + s, HW = H * W;
  int pad = 4 - s, dil = pad;
  int tid = threadIdx.x, lane = tid & 63;
  int gv = tid >> 6;
  int g = __builtin_amdgcn_readfirstlane(gv);
  int p = swz * 64 + lane;
  int py = p >> lw, px = p & (W - 1);
  const v4f* ipg4 = (const v4f*)A.in[s] + (size_t)(g * 2) * HW;  // quad 2g
  float* myred = &red[(size_t)(gv * 64 + lane) * 18];
  const float* lred = &red[lane * 18];

  // ---------------- phase A: offset conv (18 ch), partial over 8 channels
  {
    v2f accA[9];
#pragma unroll
    for (int j = 0; j < 9; ++j) accA[j] = (v2f){0.f, 0.f};
    const float* wT = A.wc[s];
#pragma unroll
    for (int ky = 0; ky < 3; ++ky) {
#pragma unroll
      for (int kx = 0; kx < 3; ++kx) {
        int k = ky * 3 + kx;
        int yy = py + ky - 1, xx = px + kx - 1;
        float msk = (yy >= 0 && yy < H && xx >= 0 && xx < W) ? 1.f : 0.f;
        int ai = min(max(yy, 0), H - 1) * W + min(max(xx, 0), W - 1);
        v4f va0 = ipg4[ai];                 // channels 8g..8g+3
        v4f va1 = ipg4[(size_t)HW + ai];    // channels 8g+4..8g+7
        const float* wkb = wT + (size_t)(k * 64 + g * 8) * 18;
#pragma unroll
        for (int e = 0; e < 4; ++e) {
          float v = va0[e] * msk;
          const v2f* w0 = (const v2f*)(wkb + e * 18);
          v2f vv = {v, v};
#pragma unroll
          for (int j = 0; j < 9; ++j) accA[j] = pkfma(w0[j], vv, accA[j]);
        }
#pragma unroll
        for (int e = 0; e < 4; ++e) {
          float v = va1[e] * msk;
          const v2f* w1 = (const v2f*)(wkb + (4 + e) * 18);
          v2f vv = {v, v};
#pragma unroll
          for (int j = 0; j < 9; ++j) accA[j] = pkfma(w1[j], vv, accA[j]);
        }
      }
    }
#pragma unroll
    for (int j = 0; j < 9; ++j) *(v2f*)(myred + 2 * j) = accA[j];
  }
  __syncthreads();
  v2f off2[9];
  {
    const v2f* bc2 = (const v2f*)A.bc[s];
#pragma unroll
    for (int j = 0; j < 9; ++j) {
      v2f v = bc2[j];
#pragma unroll
      for (int r = 0; r < 8; ++r) v += *(const v2f*)(lred + (size_t)r * 64 * 18 + 2 * j);
      off2[j] = v;
    }
  }
  __syncthreads();   // red reads done; red becomes the weight cache now

  // ---------------- stage this wave's phase-B weight slice into LDS
  // slice layout: [k][c][16] floats at red + gv*1152
  float* wls = &red[(size_t)gv * 1152];
  {
    const float* wdg = A.wd[s];
    for (int pr = lane; pr < 72; pr += 64) {
      int k = pr >> 3, c = pr & 7;
      const v4f* src = (const v4f*)(wdg + (size_t)(k * 64 + g * 8 + c) * 16);
      v4f* dst = (v4f*)(wls + (size_t)pr * 16);
      dst[0] = src[0];
      dst[1] = src[1];
      dst[2] = src[2];
      dst[3] = src[3];
    }
  }
  // no barrier needed: slice is read only by this wave (LDS ops in-order
  // within a wave; compiler inserts lgkmcnt before dependent ds_read)

  // ---------------- phase B: deformable conv (16 ch) using off2
  v2f acc2[8];
#pragma unroll
  for (int j = 0; j < 8; ++j) acc2[j] = (v2f){0.f, 0.f};
  {
#pragma unroll
    for (int ky = 0; ky < 3; ++ky) {
#pragma unroll
      for (int kx = 0; kx < 3; ++kx) {
        int k = ky * 3 + kx;
        float dy = off2[k].x;
        float dx = off2[k].y;
        float pyf = (float)(py - pad + ky * dil) + dy;
        float pxf = (float)(px - pad + kx * dil) + dx;
        float fy0 = floorf(pyf), fx0 = floorf(pxf);
        float wy = pyf - fy0, wxv = pxf - fx0;
        int y0 = (int)fy0, x0 = (int)fx0;
        float xg = (x0 >= -1 && x0 <= W - 1) ? 1.f : 0.f;
        float r0 = (1.f - wy) * ((y0 >= 0 && y0 < H) ? xg : 0.f);
        float r1 = wy * ((y0 + 1 >= 0 && y0 + 1 < H) ? xg : 0.f);
        float cl = 1.f - wxv, cr = wxv;
        bool xlo = x0 < 0, xhi = x0 > W - 2;
        float W00 = xlo ? r0 * cr : (xhi ? 0.f : r0 * cl);
        float W01 = xlo ? 0.f : (xhi ? r0 * cl : r0 * cr);
        float W10 = xlo ? r1 * cr : (xhi ? 0.f : r1 * cl);
        float W11 = xlo ? 0.f : (xhi ? r1 * cl : r1 * cr);
        int ax = min(max(x0, 0), W - 2);
        int cy0 = min(max(y0, 0), H - 1);
        int cy1 = min(max(y0 + 1, 0), H - 1);
        int A0 = cy0 * W + ax, A1 = cy1 * W + ax;
        v4f W00v = {W00, W00, W00, W00}, W01v = {W01, W01, W01, W01};
        v4f W10v = {W10, W10, W10, W10}, W11v = {W11, W11, W11, W11};
        // quad 2g (channels c=0..3 of the slice)
        {
          v4f q00 = ipg4[A0], q01 = ipg4[A0 + 1];
          v4f q10 = ipg4[A1], q11 = ipg4[A1 + 1];
          v4f sv = q00 * W00v;
          sv = pkfma4(q01, W01v, sv);
          sv = pkfma4(q10, W10v, sv);
          sv = pkfma4(q11, W11v, sv);
#pragma unroll
          for (int e = 0; e < 4; ++e) {
            const v2f* wv = (const v2f*)(wls + (size_t)(k * 8 + e) * 16);
            v2f vv = {sv[e], sv[e]};
#pragma unroll
            for (int j = 0; j < 8; ++j) acc2[j] = pkfma(wv[j], vv, acc2[j]);
          }
        }
        // quad 2g+1 (channels c=4..7 of the slice)
        {
          const v4f* ipq = ipg4 + (size_t)HW;
          v4f q00 = ipq[A0], q01 = ipq[A0 + 1];
          v4f q10 = ipq[A1], q11 = ipq[A1 + 1];
          v4f sv = q00 * W00v;
          sv = pkfma4(q01, W01v, sv);
          sv = pkfma4(q10, W10v, sv);
          sv = pkfma4(q11, W11v, sv);
#pragma unroll
          for (int e = 0; e < 4; ++e) {
            const v2f* wv = (const v2f*)(wls + (size_t)(k * 8 + 4 + e) * 16);
            v2f vv = {sv[e], sv[e]};
#pragma unroll
            for (int j = 0; j < 8; ++j) acc2[j] = pkfma(wv[j], vv, acc2[j]);
          }
        }
      }
    }
  }
  __syncthreads();   // all waves done reading weights before red is overwritten
  if (gv) {
    float* wr = &red[(size_t)((gv - 1) * 64 + lane) * 18];
#pragma unroll
    for (int j = 0; j < 8; ++j) *(v2f*)(wr + 2 * j) = acc2[j];
  }
  __syncthreads();
  if (!gv) {
    const v2f* bd2 = (const v2f*)A.bd[s];
    float* out = A.out[s];
#pragma unroll
    for (int j = 0; j < 8; ++j) {
      v2f v = acc2[j] + bd2[j];
#pragma unroll
      for (int r = 0; r < 7; ++r) v += *(const v2f*)(lred + (size_t)r * 64 * 18 + 2 * j);
      float vx = v.x, vy = v.y;
      vx = vx >= 0.f ? vx : 0.01f * vx;
      vy = vy >= 0.f ? vy : 0.01f * vy;
      out[(size_t)(2 * j) * HW + p] = vx;
      out[(size_t)(2 * j + 1) * HW + p] = vy;
    }
  }
}

// ---------------------------------------------------------------------------
// Horizontal downsample pass: a3 (16,256,256) -> t3 (16,256,64) 8 taps;
// a2 (16,128,128) -> t2 (16,128,64) 4 taps.
// ---------------------------------------------------------------------------
__global__ void k_hpass(const float* __restrict__ a2, const float* __restrict__ a3,
                        float* __restrict__ t2, float* __restrict__ t3) {
  int idx = blockIdx.x * BDIM + threadIdx.x;
  if (idx < 262144) {
    int ox = idx & 63, y = (idx >> 6) & 255, c = idx >> 14;
    float wx[8];
    int x0;
    int n = resize_taps(64, ox, 256, wx, &x0);
    const float* row = a3 + (size_t)c * 65536 + y * 256 + x0;
    float r = 0.f;
    for (int b = 0; b < n; ++b) r += wx[b] * row[b];
    t3[idx] = r;
  } else {
    int j = idx - 262144;
    if (j < 131072) {
      int ox = j & 63, y = (j >> 6) & 127, c = j >> 13;
      float wx[8];
      int x0;
      int n = resize_taps(64, ox, 128, wx, &x0);
      const float* row = a2 + (size_t)c * 16384 + y * 128 + x0;
      float r = 0.f;
      for (int b = 0; b < n; ++b) r += wx[b] * row[b];
      t2[j] = r;
    }
  }
}

__device__ __forceinline__ float gelu_f(float x) {
  return 0.5f * x * (1.f + erff(x * 0.70710678118654752f));
}

// Vertical taps + gelu combine.
__global__ void k_final2(const float* __restrict__ a0, const float* __restrict__ a1,
                         const float* __restrict__ t2, const float* __restrict__ t3,
                         float* __restrict__ out) {
  int i = blockIdx.x * BDIM + threadIdx.x;  // [0, 65536)
  int x = i & 63, y = (i >> 6) & 63, c = i >> 12;
  float x1r = resize_one(a1 + c * 1024, 32, 32, y, x, 64, 64);
  float wv[8];
  int y0;
  int n2 = resize_taps(64, y, 128, wv, &y0);
  const float* tp2 = t2 + (size_t)c * 8192 + y0 * 64 + x;
  float x2r = 0.f;
  for (int a = 0; a < n2; ++a) x2r += wv[a] * tp2[a * 64];
  int n3 = resize_taps(64, y, 256, wv, &y0);
  const float* tp3 = t3 + (size_t)c * 16384 + y0 * 64 + x;
  float x3r = 0.f;
  for (int a = 0; a < n3; ++a) x3r += wv[a] * tp3[a * 64];
  float av = a0[i];
  float l = gelu_f(x1r);
  float m = gelu_f(av - l);
  float h = gelu_f(x2r - av);
  float sv = gelu_f(x3r - x2r);
  out[i] = l;
  out[65536 + i] = m;
  out[131072 + i] = h;
  out[196608 + i] = sv;
}

static inline int cdiv(int a, int b) { return (a + b - 1) / b; }

extern "C" void kernel_launch(void* const* d_in, const int* in_sizes, int n_in,
                              void* d_out, int out_size, void* d_ws, size_t ws_size,
                              hipStream_t stream) {
  (void)in_sizes; (void)n_in; (void)out_size; (void)ws_size;
  const float* x = (const float*)d_in[0];
  const float* w_off[4] = {(const float*)d_in[1], (const float*)d_in[5],
                           (const float*)d_in[9], (const float*)d_in[13]};
  const float* b_off[4] = {(const float*)d_in[2], (const float*)d_in[6],
                           (const float*)d_in[10], (const float*)d_in[14]};
  const float* w_c[4] = {(const float*)d_in[3], (const float*)d_in[7],
                         (const float*)d_in[11], (const float*)d_in[15]};
  const float* b_c[4] = {(const float*)d_in[4], (const float*)d_in[8],
                         (const float*)d_in[12], (const float*)d_in[16]};
  float* out = (float*)d_out;

  // Workspace (floats), lifetime-aliased; peak 7,428,608 f = 29.7 MB.
  float* ws = (float*)d_ws;
  float* a0 = ws;                  // [0, 65536)
  float* a1 = ws + 65536;          // [65536, 81920)
  float* a2 = ws + 81920;          // [81920, 344064)
  float* wT = ws + 344064;         // [344064, 422400)
  float* x1q = ws + 422400;        // [422400, 487936)   dead after k_fused
  float* t3 = ws + 422400;         // ALIAS x1q+ (written post-fused)
  float* t2 = ws + 684544;         // [684544, 815616)
  float* x2q = ws + 875008;        // [875008, 1923584)
  float* x3q = ws + 1923584;       // [1923584, 6117888)
  float* a3 = ws + 6117888;        // [6117888, 7166464)
  float* xq = ws + 7166464;        // [7166464, 7428608)
  float* wTd = wT;                 // 4 x 9216
  float* wTc = wT + 36864;         // 4 x 10368

  FArgs fa;
  const float* ins[4] = {x1q, xq, x2q, x3q};
  float* as[4] = {a1, a0, a2, a3};
  for (int s = 0; s < 4; ++s) {
    fa.in[s] = ins[s];
    fa.wc[s] = wTc + s * 10368;
    fa.bc[s] = b_off[s];
    fa.wd[s] = wTd + (3 - s) * 9216;
    fa.bd[s] = b_c[3 - s];
    fa.out[s] = as[s];
  }

  k_front<<<cdiv(5648896, BDIM), BDIM, 0, stream>>>(
      x, x1q, x2q, x3q, xq, w_c[0], w_c[1], w_c[2], w_c[3],
      w_off[0], w_off[1], w_off[2], w_off[3], wT);
  k_fused<<<1360, 512, 0, stream>>>(fa);
  k_hpass<<<cdiv(262144 + 131072, BDIM), BDIM, 0, stream>>>(a2, a3, t2, t3);
  k_final2<<<cdiv(65536, BDIM), BDIM, 0, stream>>>(a0, a1, t2, t3, out);
}

// Round 19
// 171.431 us; speedup vs baseline: 1.2494x; 1.2494x over previous
//
#include <hip/hip_runtime.h>
#include <math.h>

#define BDIM 256

typedef float v2f __attribute__((ext_vector_type(2)));
typedef float v4f __attribute__((ext_vector_type(4)));

__device__ __forceinline__ v2f pkfma(v2f a, v2f b, v2f c) {
#if __has_builtin(__builtin_elementwise_fma)
  return __builtin_elementwise_fma(a, b, c);
#else
  v2f d;
  d.x = fmaf(a.x, b.x, c.x);
  d.y = fmaf(a.y, b.y, c.y);
  return d;
#endif
}

__device__ __forceinline__ v4f pkfma4(v4f a, v4f b, v4f c) {
#if __has_builtin(__builtin_elementwise_fma)
  return __builtin_elementwise_fma(a, b, c);
#else
  v4f d;
  d.x = fmaf(a.x, b.x, c.x);
  d.y = fmaf(a.y, b.y, c.y);
  d.z = fmaf(a.z, b.z, c.z);
  d.w = fmaf(a.w, b.w, c.w);
  return d;
#endif
}

// ---------------------------------------------------------------------------
// jax.image.resize (bilinear/triangle, antialias=True) tap weights.
// ---------------------------------------------------------------------------
__device__ __forceinline__ int resize_taps(int out_n, int o, int in_n,
                                           float* w, int* i0) {
  float inv_scale = (float)in_n / (float)out_n;
  float ks = inv_scale > 1.f ? inv_scale : 1.f;
  float sf = ((float)o + 0.5f) * inv_scale - 0.5f;
  int lo = (int)ceilf(sf - ks);
  int hi = (int)floorf(sf + ks);
  if (lo < 0) lo = 0;
  if (hi > in_n - 1) hi = in_n - 1;
  int n = hi - lo + 1;
  float sum = 0.f;
  for (int k = 0; k < n; ++k) {
    float t = 1.f - fabsf((float)(lo + k) - sf) / ks;
    t = t > 0.f ? t : 0.f;
    w[k] = t;
    sum += t;
  }
  float inv = 1.f / sum;
  for (int k = 0; k < n; ++k) w[k] *= inv;
  *i0 = lo;
  return n;
}

__device__ __forceinline__ float resize_one(const float* __restrict__ plane,
                                            int Hi, int Wi, int oy, int ox,
                                            int Ho, int Wo) {
  float wy[8], wx[8];
  int y0, x0;
  int ny = resize_taps(Ho, oy, Hi, wy, &y0);
  int nx = resize_taps(Wo, ox, Wi, wx, &x0);
  float acc = 0.f;
  for (int a = 0; a < ny; ++a) {
    const float* row = plane + (y0 + a) * Wi + x0;
    float r = 0.f;
    for (int b = 0; b < nx; ++b) r += wx[b] * row[b];
    acc += wy[a] * r;
  }
  return acc;
}

// Hardcoded jax 2x bilinear upsample taps (scale>1 => no antialias change).
__device__ __forceinline__ void up2(int o, int n, int* t, float* w) {
  int m = o >> 1;
  if (o == 0) { t[0] = 0; w[0] = 1.f; t[1] = 0; w[1] = 0.f; }
  else if (o == 2 * n - 1) { t[0] = n - 1; w[0] = 1.f; t[1] = n - 1; w[1] = 0.f; }
  else if (o & 1) { t[0] = m; w[0] = 0.75f; t[1] = m + 1; w[1] = 0.25f; }
  else { t[0] = m - 1; w[0] = 0.25f; t[1] = m; w[1] = 0.75f; }
}

// quad-layout store: channel c, pixel pix, plane size HW (floats)
__device__ __forceinline__ void pstore4(float* __restrict__ dst, int c, int pix,
                                        int HW, float v) {
  dst[((size_t)(c >> 2) * HW + pix) * 4 + (c & 3)] = v;
}

// ---------------------------------------------------------------------------
// FRONT: builds QUAD-CHANNEL [c/4][HW][4] copies of all conv inputs:
//   x1q, x2q (hardcoded 2x up taps), x3q (composed 2x·2x), xq, + wT transpose.
// ---------------------------------------------------------------------------
__global__ void k_front(const float* __restrict__ x, float* __restrict__ x1q,
                        float* __restrict__ x2q, float* __restrict__ x3q,
                        float* __restrict__ xq,
                        const float* __restrict__ d0, const float* __restrict__ d1,
                        const float* __restrict__ d2, const float* __restrict__ d3,
                        const float* __restrict__ c0, const float* __restrict__ c1,
                        const float* __restrict__ c2, const float* __restrict__ c3,
                        float* __restrict__ wT) {
  int idx = blockIdx.x * BDIM + threadIdx.x;
  if (idx < 65536) {
    int ox = idx & 31, oy = (idx >> 5) & 31, c = idx >> 10;
    pstore4(x1q, c, oy * 32 + ox, 1024,
            resize_one(x + c * 4096, 64, 64, oy, ox, 32, 32));
  } else if (idx < 1114112) {
    int j = idx - 65536;
    int ox = j & 127, oy = (j >> 7) & 127, c = j >> 14;
    int ty[2], tx[2];
    float twy[2], twx[2];
    up2(oy, 64, ty, twy);
    up2(ox, 64, tx, twx);
    const float* xc = x + c * 4096;
    float acc = 0.f;
#pragma unroll
    for (int a = 0; a < 2; ++a) {
      const float* row = xc + ty[a] * 64;
      acc += twy[a] * (twx[0] * row[tx[0]] + twx[1] * row[tx[1]]);
    }
    pstore4(x2q, c, oy * 128 + ox, 16384, acc);
  } else if (idx < 5308416) {
    int j = idx - 1114112;
    int ox = j & 255, oy = (j >> 8) & 255, c = j >> 16;
    int ty[2], tx[2];
    float twy[2], twx[2];
    up2(oy, 128, ty, twy);
    up2(ox, 128, tx, twx);
    int ry[4], rx[4];
    float rwy[4], rwx[4];
#pragma unroll
    for (int a = 0; a < 2; ++a) {
      int t2[2];
      float w2[2];
      up2(ty[a], 64, t2, w2);
      ry[2 * a] = t2[0]; rwy[2 * a] = twy[a] * w2[0];
      ry[2 * a + 1] = t2[1]; rwy[2 * a + 1] = twy[a] * w2[1];
      up2(tx[a], 64, t2, w2);
      rx[2 * a] = t2[0]; rwx[2 * a] = twx[a] * w2[0];
      rx[2 * a + 1] = t2[1]; rwx[2 * a + 1] = twx[a] * w2[1];
    }
    const float* xc = x + c * 4096;
    float acc = 0.f;
#pragma unroll
    for (int a = 0; a < 4; ++a) {
      const float* row = xc + ry[a] * 64;
      float r = 0.f;
#pragma unroll
      for (int b = 0; b < 4; ++b) r += rwx[b] * row[rx[b]];
      acc += rwy[a] * r;
    }
    pstore4(x3q, c, oy * 256 + ox, 65536, acc);
  } else if (idx < 5386752) {
    int w = idx - 5308416;
    if (w < 36864) {
      int i = w / 9216, r = w % 9216;
      int o = r % 16, t = r / 16, c = t % 64, k = t / 64;
      const float* s = i == 0 ? d0 : i == 1 ? d1 : i == 2 ? d2 : d3;
      wT[w] = s[(o * 64 + c) * 9 + k];
    } else {
      int j = w - 36864;
      int i = j / 10368, r = j % 10368;
      int o = r % 18, t = r / 18, c = t % 64, k = t / 64;
      const float* s = i == 0 ? c0 : i == 1 ? c1 : i == 2 ? c2 : c3;
      wT[w] = s[(o * 64 + c) * 9 + k];
    }
  } else if (idx < 5648896) {
    int j = idx - 5386752;        // copy x -> quad xq
    int c = j >> 12, pix = j & 4095;
    pstore4(xq, c, pix, 4096, x[j]);
  }
}

// ---------------------------------------------------------------------------
// FUSED offset-conv + deformable conv + leaky, all 4 scales in one grid.
// QUAD-CHANNEL inputs: one dwordx4 load = 4 channels at a pixel.
// Segments big->small; per-segment bijective XCD swizzle (bl&7)*(n/8)+(bl>>3).
// Block = 512 thr = 8 waves; wave g owns quads {2g, 2g+1} (= channels
// 8g..8g+7). Weights via wave-uniform scalar loads (L2-served; R18's LDS
// staging of weights refetched 50MB/launch + bank-conflicted + spilled).
// launch_bounds(512,4); VGPR 52 (sweet spot <=64).
// ---------------------------------------------------------------------------
struct FArgs {
  const float* in[4];   // quad-channel images
  const float* wc[4];   // conv weights [k][c][o18]
  const float* bc[4];   // conv bias
  const float* wd[4];   // deform weights [k][c][o16] (crossed)
  const float* bd[4];   // deform bias (crossed)
  float* out[4];        // a1, a0, a2, a3 (scalar CHW)
};

__global__ __launch_bounds__(512, 4) void k_fused(FArgs A) {
  __shared__ float red[8 * 64 * 18];   // 36 KB, stride 18 (2-way = free)
  int b = blockIdx.x;
  int s, b0, nseg;
  if (b < 1024)      { s = 3; b0 = 0;    nseg = 1024; }
  else if (b < 1280) { s = 2; b0 = 1024; nseg = 256; }
  else if (b < 1344) { s = 1; b0 = 1280; nseg = 64; }
  else               { s = 0; b0 = 1344; nseg = 16; }
  int bl = b - b0;
  int swz = (bl & 7) * (nseg >> 3) + (bl >> 3);
  int H = 32 << s, W = H, lw = 5 + s, HW = H * W;
  int pad = 4 - s, dil = pad;
  int tid = threadIdx.x, lane = tid & 63;
  int gv = tid >> 6;
  int g = __builtin_amdgcn_readfirstlane(gv);
  int p = swz * 64 + lane;
  int py = p >> lw, px = p & (W - 1);
  const v4f* ipg4 = (const v4f*)A.in[s] + (size_t)(g * 2) * HW;  // quad 2g
  float* myred = &red[(size_t)(gv * 64 + lane) * 18];
  const float* lred = &red[lane * 18];

  // ---------------- phase A: offset conv (18 ch), partial over 8 channels
  {
    v2f accA[9];
#pragma unroll
    for (int j = 0; j < 9; ++j) accA[j] = (v2f){0.f, 0.f};
    const float* wT = A.wc[s];
#pragma unroll
    for (int ky = 0; ky < 3; ++ky) {
#pragma unroll
      for (int kx = 0; kx < 3; ++kx) {
        int k = ky * 3 + kx;
        int yy = py + ky - 1, xx = px + kx - 1;
        float msk = (yy >= 0 && yy < H && xx >= 0 && xx < W) ? 1.f : 0.f;
        int ai = min(max(yy, 0), H - 1) * W + min(max(xx, 0), W - 1);
        v4f va0 = ipg4[ai];                 // channels 8g..8g+3
        v4f va1 = ipg4[(size_t)HW + ai];    // channels 8g+4..8g+7
        const float* wkb = wT + (size_t)(k * 64 + g * 8) * 18;
#pragma unroll
        for (int e = 0; e < 4; ++e) {
          float v = va0[e] * msk;
          const v2f* w0 = (const v2f*)(wkb + e * 18);
          v2f vv = {v, v};
#pragma unroll
          for (int j = 0; j < 9; ++j) accA[j] = pkfma(w0[j], vv, accA[j]);
        }
#pragma unroll
        for (int e = 0; e < 4; ++e) {
          float v = va1[e] * msk;
          const v2f* w1 = (const v2f*)(wkb + (4 + e) * 18);
          v2f vv = {v, v};
#pragma unroll
          for (int j = 0; j < 9; ++j) accA[j] = pkfma(w1[j], vv, accA[j]);
        }
      }
    }
#pragma unroll
    for (int j = 0; j < 9; ++j) *(v2f*)(myred + 2 * j) = accA[j];
  }
  __syncthreads();
  v2f off2[9];
  {
    const v2f* bc2 = (const v2f*)A.bc[s];
#pragma unroll
    for (int j = 0; j < 9; ++j) {
      v2f v = bc2[j];
#pragma unroll
      for (int r = 0; r < 8; ++r) v += *(const v2f*)(lred + (size_t)r * 64 * 18 + 2 * j);
      off2[j] = v;
    }
  }
  __syncthreads();   // all reads of red done before phase-B overwrites

  // ---------------- phase B: deformable conv (16 ch) using off2
  v2f acc2[8];
#pragma unroll
  for (int j = 0; j < 8; ++j) acc2[j] = (v2f){0.f, 0.f};
  {
    const float* wT = A.wd[s];
#pragma unroll
    for (int ky = 0; ky < 3; ++ky) {
#pragma unroll
      for (int kx = 0; kx < 3; ++kx) {
        int k = ky * 3 + kx;
        float dy = off2[k].x;
        float dx = off2[k].y;
        float pyf = (float)(py - pad + ky * dil) + dy;
        float pxf = (float)(px - pad + kx * dil) + dx;
        float fy0 = floorf(pyf), fx0 = floorf(pxf);
        float wy = pyf - fy0, wxv = pxf - fx0;
        int y0 = (int)fy0, x0 = (int)fx0;
        float xg = (x0 >= -1 && x0 <= W - 1) ? 1.f : 0.f;
        float r0 = (1.f - wy) * ((y0 >= 0 && y0 < H) ? xg : 0.f);
        float r1 = wy * ((y0 + 1 >= 0 && y0 + 1 < H) ? xg : 0.f);
        float cl = 1.f - wxv, cr = wxv;
        bool xlo = x0 < 0, xhi = x0 > W - 2;
        float W00 = xlo ? r0 * cr : (xhi ? 0.f : r0 * cl);
        float W01 = xlo ? 0.f : (xhi ? r0 * cl : r0 * cr);
        float W10 = xlo ? r1 * cr : (xhi ? 0.f : r1 * cl);
        float W11 = xlo ? 0.f : (xhi ? r1 * cl : r1 * cr);
        int ax = min(max(x0, 0), W - 2);
        int cy0 = min(max(y0, 0), H - 1);
        int cy1 = min(max(y0 + 1, 0), H - 1);
        int A0 = cy0 * W + ax, A1 = cy1 * W + ax;
        v4f W00v = {W00, W00, W00, W00}, W01v = {W01, W01, W01, W01};
        v4f W10v = {W10, W10, W10, W10}, W11v = {W11, W11, W11, W11};
        const float* wkb = wT + (size_t)(k * 64 + g * 8) * 16;
        // quad 2g (channels 8g..8g+3): 4 loads, interp, outer product
        {
          v4f q00 = ipg4[A0], q01 = ipg4[A0 + 1];
          v4f q10 = ipg4[A1], q11 = ipg4[A1 + 1];
          v4f sv = q00 * W00v;
          sv = pkfma4(q01, W01v, sv);
          sv = pkfma4(q10, W10v, sv);
          sv = pkfma4(q11, W11v, sv);
#pragma unroll
          for (int e = 0; e < 4; ++e) {
            const v2f* w0 = (const v2f*)(wkb + e * 16);
            v2f vv = {sv[e], sv[e]};
#pragma unroll
            for (int j = 0; j < 8; ++j) acc2[j] = pkfma(w0[j], vv, acc2[j]);
          }
        }
        // quad 2g+1 (channels 8g+4..8g+7)
        {
          const v4f* ipq = ipg4 + (size_t)HW;
          v4f q00 = ipq[A0], q01 = ipq[A0 + 1];
          v4f q10 = ipq[A1], q11 = ipq[A1 + 1];
          v4f sv = q00 * W00v;
          sv = pkfma4(q01, W01v, sv);
          sv = pkfma4(q10, W10v, sv);
          sv = pkfma4(q11, W11v, sv);
#pragma unroll
          for (int e = 0; e < 4; ++e) {
            const v2f* w1 = (const v2f*)(wkb + (4 + e) * 16);
            v2f vv = {sv[e], sv[e]};
#pragma unroll
            for (int j = 0; j < 8; ++j) acc2[j] = pkfma(w1[j], vv, acc2[j]);
          }
        }
      }
    }
  }
  if (gv) {
    float* wr = &red[(size_t)((gv - 1) * 64 + lane) * 18];
#pragma unroll
    for (int j = 0; j < 8; ++j) *(v2f*)(wr + 2 * j) = acc2[j];
  }
  __syncthreads();
  if (!gv) {
    const v2f* bd2 = (const v2f*)A.bd[s];
    float* out = A.out[s];
#pragma unroll
    for (int j = 0; j < 8; ++j) {
      v2f v = acc2[j] + bd2[j];
#pragma unroll
      for (int r = 0; r < 7; ++r) v += *(const v2f*)(lred + (size_t)r * 64 * 18 + 2 * j);
      float vx = v.x, vy = v.y;
      vx = vx >= 0.f ? vx : 0.01f * vx;
      vy = vy >= 0.f ? vy : 0.01f * vy;
      out[(size_t)(2 * j) * HW + p] = vx;
      out[(size_t)(2 * j + 1) * HW + p] = vy;
    }
  }
}

// ---------------------------------------------------------------------------
// Horizontal downsample pass: a3 (16,256,256) -> t3 (16,256,64) 8 taps;
// a2 (16,128,128) -> t2 (16,128,64) 4 taps.
// ---------------------------------------------------------------------------
__global__ void k_hpass(const float* __restrict__ a2, const float* __restrict__ a3,
                        float* __restrict__ t2, float* __restrict__ t3) {
  int idx = blockIdx.x * BDIM + threadIdx.x;
  if (idx < 262144) {
    int ox = idx & 63, y = (idx >> 6) & 255, c = idx >> 14;
    float wx[8];
    int x0;
    int n = resize_taps(64, ox, 256, wx, &x0);
    const float* row = a3 + (size_t)c * 65536 + y * 256 + x0;
    float r = 0.f;
    for (int b = 0; b < n; ++b) r += wx[b] * row[b];
    t3[idx] = r;
  } else {
    int j = idx - 262144;
    if (j < 131072) {
      int ox = j & 63, y = (j >> 6) & 127, c = j >> 13;
      float wx[8];
      int x0;
      int n = resize_taps(64, ox, 128, wx, &x0);
      const float* row = a2 + (size_t)c * 16384 + y * 128 + x0;
      float r = 0.f;
      for (int b = 0; b < n; ++b) r += wx[b] * row[b];
      t2[j] = r;
    }
  }
}

__device__ __forceinline__ float gelu_f(float x) {
  return 0.5f * x * (1.f + erff(x * 0.70710678118654752f));
}

// Vertical taps + gelu combine.
__global__ void k_final2(const float* __restrict__ a0, const float* __restrict__ a1,
                         const float* __restrict__ t2, const float* __restrict__ t3,
                         float* __restrict__ out) {
  int i = blockIdx.x * BDIM + threadIdx.x;  // [0, 65536)
  int x = i & 63, y = (i >> 6) & 63, c = i >> 12;
  float x1r = resize_one(a1 + c * 1024, 32, 32, y, x, 64, 64);
  float wv[8];
  int y0;
  int n2 = resize_taps(64, y, 128, wv, &y0);
  const float* tp2 = t2 + (size_t)c * 8192 + y0 * 64 + x;
  float x2r = 0.f;
  for (int a = 0; a < n2; ++a) x2r += wv[a] * tp2[a * 64];
  int n3 = resize_taps(64, y, 256, wv, &y0);
  const float* tp3 = t3 + (size_t)c * 16384 + y0 * 64 + x;
  float x3r = 0.f;
  for (int a = 0; a < n3; ++a) x3r += wv[a] * tp3[a * 64];
  float av = a0[i];
  float l = gelu_f(x1r);
  float m = gelu_f(av - l);
  float h = gelu_f(x2r - av);
  float sv = gelu_f(x3r - x2r);
  out[i] = l;
  out[65536 + i] = m;
  out[131072 + i] = h;
  out[196608 + i] = sv;
}

static inline int cdiv(int a, int b) { return (a + b - 1) / b; }

extern "C" void kernel_launch(void* const* d_in, const int* in_sizes, int n_in,
                              void* d_out, int out_size, void* d_ws, size_t ws_size,
                              hipStream_t stream) {
  (void)in_sizes; (void)n_in; (void)out_size; (void)ws_size;
  const float* x = (const float*)d_in[0];
  const float* w_off[4] = {(const float*)d_in[1], (const float*)d_in[5],
                           (const float*)d_in[9], (const float*)d_in[13]};
  const float* b_off[4] = {(const float*)d_in[2], (const float*)d_in[6],
                           (const float*)d_in[10], (const float*)d_in[14]};
  const float* w_c[4] = {(const float*)d_in[3], (const float*)d_in[7],
                         (const float*)d_in[11], (const float*)d_in[15]};
  const float* b_c[4] = {(const float*)d_in[4], (const float*)d_in[8],
                         (const float*)d_in[12], (const float*)d_in[16]};
  float* out = (float*)d_out;

  // Workspace (floats), lifetime-aliased; peak 7,428,608 f = 29.7 MB.
  float* ws = (float*)d_ws;
  float* a0 = ws;                  // [0, 65536)
  float* a1 = ws + 65536;          // [65536, 81920)
  float* a2 = ws + 81920;          // [81920, 344064)
  float* wT = ws + 344064;         // [344064, 422400)
  float* x1q = ws + 422400;        // [422400, 487936)   dead after k_fused
  float* t3 = ws + 422400;         // ALIAS x1q+ (written post-fused)
  float* t2 = ws + 684544;         // [684544, 815616)
  float* x2q = ws + 875008;        // [875008, 1923584)
  float* x3q = ws + 1923584;       // [1923584, 6117888)
  float* a3 = ws + 6117888;        // [6117888, 7166464)
  float* xq = ws + 7166464;        // [7166464, 7428608)
  float* wTd = wT;                 // 4 x 9216
  float* wTc = wT + 36864;         // 4 x 10368

  FArgs fa;
  const float* ins[4] = {x1q, xq, x2q, x3q};
  float* as[4] = {a1, a0, a2, a3};
  for (int s = 0; s < 4; ++s) {
    fa.in[s] = ins[s];
    fa.wc[s] = wTc + s * 10368;
    fa.bc[s] = b_off[s];
    fa.wd[s] = wTd + (3 - s) * 9216;
    fa.bd[s] = b_c[3 - s];
    fa.out[s] = as[s];
  }

  k_front<<<cdiv(5648896, BDIM), BDIM, 0, stream>>>(
      x, x1q, x2q, x3q, xq, w_c[0], w_c[1], w_c[2], w_c[3],
      w_off[0], w_off[1], w_off[2], w_off[3], wT);
  k_fused<<<1360, 512, 0, stream>>>(fa);
  k_hpass<<<cdiv(262144 + 131072, BDIM), BDIM, 0, stream>>>(a2, a3, t2, t3);
  k_final2<<<cdiv(65536, BDIM), BDIM, 0, stream>>>(a0, a1, t2, t3, out);
}

// Round 20
// 169.421 us; speedup vs baseline: 1.2642x; 1.0119x over previous
//
#include <hip/hip_runtime.h>
#include <math.h>

#define BDIM 256

typedef float v2f __attribute__((ext_vector_type(2)));
typedef float v4f __attribute__((ext_vector_type(4)));

__device__ __forceinline__ v2f pkfma(v2f a, v2f b, v2f c) {
#if __has_builtin(__builtin_elementwise_fma)
  return __builtin_elementwise_fma(a, b, c);
#else
  v2f d;
  d.x = fmaf(a.x, b.x, c.x);
  d.y = fmaf(a.y, b.y, c.y);
  return d;
#endif
}

__device__ __forceinline__ v4f pkfma4(v4f a, v4f b, v4f c) {
#if __has_builtin(__builtin_elementwise_fma)
  return __builtin_elementwise_fma(a, b, c);
#else
  v4f d;
  d.x = fmaf(a.x, b.x, c.x);
  d.y = fmaf(a.y, b.y, c.y);
  d.z = fmaf(a.z, b.z, c.z);
  d.w = fmaf(a.w, b.w, c.w);
  return d;
#endif
}

// ---------------------------------------------------------------------------
// jax.image.resize (bilinear/triangle, antialias=True) tap weights.
// ---------------------------------------------------------------------------
__device__ __forceinline__ int resize_taps(int out_n, int o, int in_n,
                                           float* w, int* i0) {
  float inv_scale = (float)in_n / (float)out_n;
  float ks = inv_scale > 1.f ? inv_scale : 1.f;
  float sf = ((float)o + 0.5f) * inv_scale - 0.5f;
  int lo = (int)ceilf(sf - ks);
  int hi = (int)floorf(sf + ks);
  if (lo < 0) lo = 0;
  if (hi > in_n - 1) hi = in_n - 1;
  int n = hi - lo + 1;
  float sum = 0.f;
  for (int k = 0; k < n; ++k) {
    float t = 1.f - fabsf((float)(lo + k) - sf) / ks;
    t = t > 0.f ? t : 0.f;
    w[k] = t;
    sum += t;
  }
  float inv = 1.f / sum;
  for (int k = 0; k < n; ++k) w[k] *= inv;
  *i0 = lo;
  return n;
}

__device__ __forceinline__ float resize_one(const float* __restrict__ plane,
                                            int Hi, int Wi, int oy, int ox,
                                            int Ho, int Wo) {
  float wy[8], wx[8];
  int y0, x0;
  int ny = resize_taps(Ho, oy, Hi, wy, &y0);
  int nx = resize_taps(Wo, ox, Wi, wx, &x0);
  float acc = 0.f;
  for (int a = 0; a < ny; ++a) {
    const float* row = plane + (y0 + a) * Wi + x0;
    float r = 0.f;
    for (int b = 0; b < nx; ++b) r += wx[b] * row[b];
    acc += wy[a] * r;
  }
  return acc;
}

// Hardcoded jax 2x bilinear upsample taps (scale>1 => no antialias change).
__device__ __forceinline__ void up2(int o, int n, int* t, float* w) {
  int m = o >> 1;
  if (o == 0) { t[0] = 0; w[0] = 1.f; t[1] = 0; w[1] = 0.f; }
  else if (o == 2 * n - 1) { t[0] = n - 1; w[0] = 1.f; t[1] = n - 1; w[1] = 0.f; }
  else if (o & 1) { t[0] = m; w[0] = 0.75f; t[1] = m + 1; w[1] = 0.25f; }
  else { t[0] = m - 1; w[0] = 0.25f; t[1] = m; w[1] = 0.75f; }
}

// ---------------------------------------------------------------------------
// FRONT: builds QUAD-CHANNEL [c/4][HW][4] copies of all conv inputs.
// One thread per QUAD-pixel: tap geometry computed once, 4 channels gathered,
// ONE coalesced 16B v4f store (vs 4 scattered 4B stores before).
// Segments: x1q 16384 | x2q 262144 | x3q 1048576 | xq 65536 | wT 78336.
// ---------------------------------------------------------------------------
__global__ void k_front(const float* __restrict__ x, float* __restrict__ x1q,
                        float* __restrict__ x2q, float* __restrict__ x3q,
                        float* __restrict__ xq,
                        const float* __restrict__ d0, const float* __restrict__ d1,
                        const float* __restrict__ d2, const float* __restrict__ d3,
                        const float* __restrict__ c0, const float* __restrict__ c1,
                        const float* __restrict__ c2, const float* __restrict__ c3,
                        float* __restrict__ wT) {
  int idx = blockIdx.x * BDIM + threadIdx.x;
  if (idx < 16384) {                       // x1q: 64->32 antialias downscale
    int q = idx >> 10, pix = idx & 1023;
    int oy = pix >> 5, ox = pix & 31;
    v4f v;
#pragma unroll
    for (int e = 0; e < 4; ++e)
      v[e] = resize_one(x + (4 * q + e) * 4096, 64, 64, oy, ox, 32, 32);
    *(v4f*)(x1q + ((size_t)q * 1024 + pix) * 4) = v;
  } else if (idx < 278528) {               // x2q: 64->128 2x up
    int j = idx - 16384;
    int q = j >> 14, pix = j & 16383;
    int oy = pix >> 7, ox = pix & 127;
    int ty[2], tx[2];
    float twy[2], twx[2];
    up2(oy, 64, ty, twy);
    up2(ox, 64, tx, twx);
    v4f v;
#pragma unroll
    for (int e = 0; e < 4; ++e) {
      const float* xc = x + (4 * q + e) * 4096;
      float acc = 0.f;
#pragma unroll
      for (int a = 0; a < 2; ++a) {
        const float* row = xc + ty[a] * 64;
        acc += twy[a] * (twx[0] * row[tx[0]] + twx[1] * row[tx[1]]);
      }
      v[e] = acc;
    }
    *(v4f*)(x2q + ((size_t)q * 16384 + pix) * 4) = v;
  } else if (idx < 1327104) {              // x3q: 64->256 composed 2x·2x
    int j = idx - 278528;
    int q = j >> 16, pix = j & 65535;
    int oy = pix >> 8, ox = pix & 255;
    int ty[2], tx[2];
    float twy[2], twx[2];
    up2(oy, 128, ty, twy);
    up2(ox, 128, tx, twx);
    int ry[4], rx[4];
    float rwy[4], rwx[4];
#pragma unroll
    for (int a = 0; a < 2; ++a) {
      int t2[2];
      float w2[2];
      up2(ty[a], 64, t2, w2);
      ry[2 * a] = t2[0]; rwy[2 * a] = twy[a] * w2[0];
      ry[2 * a + 1] = t2[1]; rwy[2 * a + 1] = twy[a] * w2[1];
      up2(tx[a], 64, t2, w2);
      rx[2 * a] = t2[0]; rwx[2 * a] = twx[a] * w2[0];
      rx[2 * a + 1] = t2[1]; rwx[2 * a + 1] = twx[a] * w2[1];
    }
    v4f v;
#pragma unroll
    for (int e = 0; e < 4; ++e) {
      const float* xc = x + (4 * q + e) * 4096;
      float acc = 0.f;
#pragma unroll
      for (int a = 0; a < 4; ++a) {
        const float* row = xc + ry[a] * 64;
        float r = 0.f;
#pragma unroll
        for (int b = 0; b < 4; ++b) r += rwx[b] * row[rx[b]];
        acc += rwy[a] * r;
      }
      v[e] = acc;
    }
    *(v4f*)(x3q + ((size_t)q * 65536 + pix) * 4) = v;
  } else if (idx < 1392640) {              // xq: copy x -> quad layout
    int j = idx - 1327104;
    int q = j >> 12, pix = j & 4095;
    v4f v;
#pragma unroll
    for (int e = 0; e < 4; ++e) v[e] = x[(4 * q + e) * 4096 + pix];
    *(v4f*)(xq + ((size_t)q * 4096 + pix) * 4) = v;
  } else if (idx < 1470976) {              // weight transpose -> [k][c][o]
    int w = idx - 1392640;
    if (w < 36864) {
      int i = w / 9216, r = w % 9216;
      int o = r % 16, t = r / 16, c = t % 64, k = t / 64;
      const float* s = i == 0 ? d0 : i == 1 ? d1 : i == 2 ? d2 : d3;
      wT[w] = s[(o * 64 + c) * 9 + k];
    } else {
      int j = w - 36864;
      int i = j / 10368, r = j % 10368;
      int o = r % 18, t = r / 18, c = t % 64, k = t / 64;
      const float* s = i == 0 ? c0 : i == 1 ? c1 : i == 2 ? c2 : c3;
      wT[w] = s[(o * 64 + c) * 9 + k];
    }
  }
}

// ---------------------------------------------------------------------------
// FUSED offset-conv + deformable conv + leaky, all 4 scales in one grid.
// (FROZEN at R19 best: 137 µs, FETCH 18.5MB, VGPR 52, 0 conflicts.)
// QUAD-CHANNEL inputs: one dwordx4 load = 4 channels at a pixel.
// Segments big->small; per-segment bijective XCD swizzle (bl&7)*(n/8)+(bl>>3).
// Block = 512 thr = 8 waves; wave g owns quads {2g, 2g+1}. Weights via
// wave-uniform scalar loads (L2-served). launch_bounds(512,4); VGPR<=64.
// ---------------------------------------------------------------------------
struct FArgs {
  const float* in[4];   // quad-channel images
  const float* wc[4];   // conv weights [k][c][o18]
  const float* bc[4];   // conv bias
  const float* wd[4];   // deform weights [k][c][o16] (crossed)
  const float* bd[4];   // deform bias (crossed)
  float* out[4];        // a1, a0, a2, a3 (scalar CHW)
};

__global__ __launch_bounds__(512, 4) void k_fused(FArgs A) {
  __shared__ float red[8 * 64 * 18];   // 36 KB, stride 18 (2-way = free)
  int b = blockIdx.x;
  int s, b0, nseg;
  if (b < 1024)      { s = 3; b0 = 0;    nseg = 1024; }
  else if (b < 1280) { s = 2; b0 = 1024; nseg = 256; }
  else if (b < 1344) { s = 1; b0 = 1280; nseg = 64; }
  else               { s = 0; b0 = 1344; nseg = 16; }
  int bl = b - b0;
  int swz = (bl & 7) * (nseg >> 3) + (bl >> 3);
  int H = 32 << s, W = H, lw = 5 + s, HW = H * W;
  int pad = 4 - s, dil = pad;
  int tid = threadIdx.x, lane = tid & 63;
  int gv = tid >> 6;
  int g = __builtin_amdgcn_readfirstlane(gv);
  int p = swz * 64 + lane;
  int py = p >> lw, px = p & (W - 1);
  const v4f* ipg4 = (const v4f*)A.in[s] + (size_t)(g * 2) * HW;  // quad 2g
  float* myred = &red[(size_t)(gv * 64 + lane) * 18];
  const float* lred = &red[lane * 18];

  // ---------------- phase A: offset conv (18 ch), partial over 8 channels
  {
    v2f accA[9];
#pragma unroll
    for (int j = 0; j < 9; ++j) accA[j] = (v2f){0.f, 0.f};
    const float* wT = A.wc[s];
#pragma unroll
    for (int ky = 0; ky < 3; ++ky) {
#pragma unroll
      for (int kx = 0; kx < 3; ++kx) {
        int k = ky * 3 + kx;
        int yy = py + ky - 1, xx = px + kx - 1;
        float msk = (yy >= 0 && yy < H && xx >= 0 && xx < W) ? 1.f : 0.f;
        int ai = min(max(yy, 0), H - 1) * W + min(max(xx, 0), W - 1);
        v4f va0 = ipg4[ai];                 // channels 8g..8g+3
        v4f va1 = ipg4[(size_t)HW + ai];    // channels 8g+4..8g+7
        const float* wkb = wT + (size_t)(k * 64 + g * 8) * 18;
#pragma unroll
        for (int e = 0; e < 4; ++e) {
          float v = va0[e] * msk;
          const v2f* w0 = (const v2f*)(wkb + e * 18);
          v2f vv = {v, v};
#pragma unroll
          for (int j = 0; j < 9; ++j) accA[j] = pkfma(w0[j], vv, accA[j]);
        }
#pragma unroll
        for (int e = 0; e < 4; ++e) {
          float v = va1[e] * msk;
          const v2f* w1 = (const v2f*)(wkb + (4 + e) * 18);
          v2f vv = {v, v};
#pragma unroll
          for (int j = 0; j < 9; ++j) accA[j] = pkfma(w1[j], vv, accA[j]);
        }
      }
    }
#pragma unroll
    for (int j = 0; j < 9; ++j) *(v2f*)(myred + 2 * j) = accA[j];
  }
  __syncthreads();
  v2f off2[9];
  {
    const v2f* bc2 = (const v2f*)A.bc[s];
#pragma unroll
    for (int j = 0; j < 9; ++j) {
      v2f v = bc2[j];
#pragma unroll
      for (int r = 0; r < 8; ++r) v += *(const v2f*)(lred + (size_t)r * 64 * 18 + 2 * j);
      off2[j] = v;
    }
  }
  __syncthreads();   // all reads of red done before phase-B overwrites

  // ---------------- phase B: deformable conv (16 ch) using off2
  v2f acc2[8];
#pragma unroll
  for (int j = 0; j < 8; ++j) acc2[j] = (v2f){0.f, 0.f};
  {
    const float* wT = A.wd[s];
#pragma unroll
    for (int ky = 0; ky < 3; ++ky) {
#pragma unroll
      for (int kx = 0; kx < 3; ++kx) {
        int k = ky * 3 + kx;
        float dy = off2[k].x;
        float dx = off2[k].y;
        float pyf = (float)(py - pad + ky * dil) + dy;
        float pxf = (float)(px - pad + kx * dil) + dx;
        float fy0 = floorf(pyf), fx0 = floorf(pxf);
        float wy = pyf - fy0, wxv = pxf - fx0;
        int y0 = (int)fy0, x0 = (int)fx0;
        float xg = (x0 >= -1 && x0 <= W - 1) ? 1.f : 0.f;
        float r0 = (1.f - wy) * ((y0 >= 0 && y0 < H) ? xg : 0.f);
        float r1 = wy * ((y0 + 1 >= 0 && y0 + 1 < H) ? xg : 0.f);
        float cl = 1.f - wxv, cr = wxv;
        bool xlo = x0 < 0, xhi = x0 > W - 2;
        float W00 = xlo ? r0 * cr : (xhi ? 0.f : r0 * cl);
        float W01 = xlo ? 0.f : (xhi ? r0 * cl : r0 * cr);
        float W10 = xlo ? r1 * cr : (xhi ? 0.f : r1 * cl);
        float W11 = xlo ? 0.f : (xhi ? r1 * cl : r1 * cr);
        int ax = min(max(x0, 0), W - 2);
        int cy0 = min(max(y0, 0), H - 1);
        int cy1 = min(max(y0 + 1, 0), H - 1);
        int A0 = cy0 * W + ax, A1 = cy1 * W + ax;
        v4f W00v = {W00, W00, W00, W00}, W01v = {W01, W01, W01, W01};
        v4f W10v = {W10, W10, W10, W10}, W11v = {W11, W11, W11, W11};
        const float* wkb = wT + (size_t)(k * 64 + g * 8) * 16;
        // quad 2g (channels 8g..8g+3): 4 loads, interp, outer product
        {
          v4f q00 = ipg4[A0], q01 = ipg4[A0 + 1];
          v4f q10 = ipg4[A1], q11 = ipg4[A1 + 1];
          v4f sv = q00 * W00v;
          sv = pkfma4(q01, W01v, sv);
          sv = pkfma4(q10, W10v, sv);
          sv = pkfma4(q11, W11v, sv);
#pragma unroll
          for (int e = 0; e < 4; ++e) {
            const v2f* w0 = (const v2f*)(wkb + e * 16);
            v2f vv = {sv[e], sv[e]};
#pragma unroll
            for (int j = 0; j < 8; ++j) acc2[j] = pkfma(w0[j], vv, acc2[j]);
          }
        }
        // quad 2g+1 (channels 8g+4..8g+7)
        {
          const v4f* ipq = ipg4 + (size_t)HW;
          v4f q00 = ipq[A0], q01 = ipq[A0 + 1];
          v4f q10 = ipq[A1], q11 = ipq[A1 + 1];
          v4f sv = q00 * W00v;
          sv = pkfma4(q01, W01v, sv);
          sv = pkfma4(q10, W10v, sv);
          sv = pkfma4(q11, W11v, sv);
#pragma unroll
          for (int e = 0; e < 4; ++e) {
            const v2f* w1 = (const v2f*)(wkb + (4 + e) * 16);
            v2f vv = {sv[e], sv[e]};
#pragma unroll
            for (int j = 0; j < 8; ++j) acc2[j] = pkfma(w1[j], vv, acc2[j]);
          }
        }
      }
    }
  }
  if (gv) {
    float* wr = &red[(size_t)((gv - 1) * 64 + lane) * 18];
#pragma unroll
    for (int j = 0; j < 8; ++j) *(v2f*)(wr + 2 * j) = acc2[j];
  }
  __syncthreads();
  if (!gv) {
    const v2f* bd2 = (const v2f*)A.bd[s];
    float* out = A.out[s];
#pragma unroll
    for (int j = 0; j < 8; ++j) {
      v2f v = acc2[j] + bd2[j];
#pragma unroll
      for (int r = 0; r < 7; ++r) v += *(const v2f*)(lred + (size_t)r * 64 * 18 + 2 * j);
      float vx = v.x, vy = v.y;
      vx = vx >= 0.f ? vx : 0.01f * vx;
      vy = vy >= 0.f ? vy : 0.01f * vy;
      out[(size_t)(2 * j) * HW + p] = vx;
      out[(size_t)(2 * j + 1) * HW + p] = vy;
    }
  }
}

// ---------------------------------------------------------------------------
// Horizontal downsample pass: a3 (16,256,256) -> t3 (16,256,64) 8 taps;
// a2 (16,128,128) -> t2 (16,128,64) 4 taps.
// ---------------------------------------------------------------------------
__global__ void k_hpass(const float* __restrict__ a2, const float* __restrict__ a3,
                        float* __restrict__ t2, float* __restrict__ t3) {
  int idx = blockIdx.x * BDIM + threadIdx.x;
  if (idx < 262144) {
    int ox = idx & 63, y = (idx >> 6) & 255, c = idx >> 14;
    float wx[8];
    int x0;
    int n = resize_taps(64, ox, 256, wx, &x0);
    const float* row = a3 + (size_t)c * 65536 + y * 256 + x0;
    float r = 0.f;
    for (int b = 0; b < n; ++b) r += wx[b] * row[b];
    t3[idx] = r;
  } else {
    int j = idx - 262144;
    if (j < 131072) {
      int ox = j & 63, y = (j >> 6) & 127, c = j >> 13;
      float wx[8];
      int x0;
      int n = resize_taps(64, ox, 128, wx, &x0);
      const float* row = a2 + (size_t)c * 16384 + y * 128 + x0;
      float r = 0.f;
      for (int b = 0; b < n; ++b) r += wx[b] * row[b];
      t2[j] = r;
    }
  }
}

__device__ __forceinline__ float gelu_f(float x) {
  return 0.5f * x * (1.f + erff(x * 0.70710678118654752f));
}

// Vertical taps + gelu combine.
__global__ void k_final2(const float* __restrict__ a0, const float* __restrict__ a1,
                         const float* __restrict__ t2, const float* __restrict__ t3,
                         float* __restrict__ out) {
  int i = blockIdx.x * BDIM + threadIdx.x;  // [0, 65536)
  int x = i & 63, y = (i >> 6) & 63, c = i >> 12;
  float x1r = resize_one(a1 + c * 1024, 32, 32, y, x, 64, 64);
  float wv[8];
  int y0;
  int n2 = resize_taps(64, y, 128, wv, &y0);
  const float* tp2 = t2 + (size_t)c * 8192 + y0 * 64 + x;
  float x2r = 0.f;
  for (int a = 0; a < n2; ++a) x2r += wv[a] * tp2[a * 64];
  int n3 = resize_taps(64, y, 256, wv, &y0);
  const float* tp3 = t3 + (size_t)c * 16384 + y0 * 64 + x;
  float x3r = 0.f;
  for (int a = 0; a < n3; ++a) x3r += wv[a] * tp3[a * 64];
  float av = a0[i];
  float l = gelu_f(x1r);
  float m = gelu_f(av - l);
  float h = gelu_f(x2r - av);
  float sv = gelu_f(x3r - x2r);
  out[i] = l;
  out[65536 + i] = m;
  out[131072 + i] = h;
  out[196608 + i] = sv;
}

static inline int cdiv(int a, int b) { return (a + b - 1) / b; }

extern "C" void kernel_launch(void* const* d_in, const int* in_sizes, int n_in,
                              void* d_out, int out_size, void* d_ws, size_t ws_size,
                              hipStream_t stream) {
  (void)in_sizes; (void)n_in; (void)out_size; (void)ws_size;
  const float* x = (const float*)d_in[0];
  const float* w_off[4] = {(const float*)d_in[1], (const float*)d_in[5],
                           (const float*)d_in[9], (const float*)d_in[13]};
  const float* b_off[4] = {(const float*)d_in[2], (const float*)d_in[6],
                           (const float*)d_in[10], (const float*)d_in[14]};
  const float* w_c[4] = {(const float*)d_in[3], (const float*)d_in[7],
                         (const float*)d_in[11], (const float*)d_in[15]};
  const float* b_c[4] = {(const float*)d_in[4], (const float*)d_in[8],
                         (const float*)d_in[12], (const float*)d_in[16]};
  float* out = (float*)d_out;

  // Workspace (floats), lifetime-aliased; peak 7,428,608 f = 29.7 MB.
  float* ws = (float*)d_ws;
  float* a0 = ws;                  // [0, 65536)
  float* a1 = ws + 65536;          // [65536, 81920)
  float* a2 = ws + 81920;          // [81920, 344064)
  float* wT = ws + 344064;         // [344064, 422400)
  float* x1q = ws + 422400;        // [422400, 487936)   dead after k_fused
  float* t3 = ws + 422400;         // ALIAS x1q+ (written post-fused)
  float* t2 = ws + 684544;         // [684544, 815616)
  float* x2q = ws + 875008;        // [875008, 1923584)
  float* x3q = ws + 1923584;       // [1923584, 6117888)
  float* a3 = ws + 6117888;        // [6117888, 7166464)
  float* xq = ws + 7166464;        // [7166464, 7428608)
  float* wTd = wT;                 // 4 x 9216
  float* wTc = wT + 36864;         // 4 x 10368

  FArgs fa;
  const float* ins[4] = {x1q, xq, x2q, x3q};
  float* as[4] = {a1, a0, a2, a3};
  for (int s = 0; s < 4; ++s) {
    fa.in[s] = ins[s];
    fa.wc[s] = wTc + s * 10368;
    fa.bc[s] = b_off[s];
    fa.wd[s] = wTd + (3 - s) * 9216;
    fa.bd[s] = b_c[3 - s];
    fa.out[s] = as[s];
  }

  k_front<<<cdiv(1470976, BDIM), BDIM, 0, stream>>>(
      x, x1q, x2q, x3q, xq, w_c[0], w_c[1], w_c[2], w_c[3],
      w_off[0], w_off[1], w_off[2], w_off[3], wT);
  k_fused<<<1360, 512, 0, stream>>>(fa);
  k_hpass<<<cdiv(262144 + 131072, BDIM), BDIM, 0, stream>>>(a2, a3, t2, t3);
  k_final2<<<cdiv(65536, BDIM), BDIM, 0, stream>>>(a0, a1, t2, t3, out);
}